// Round 4
// baseline (959.499 us; speedup 1.0000x reference)
//
#include <hip/hip_runtime.h>
#include <hip/hip_fp16.h>

#define T_TOK 8192
#define H_DIM 1024
#define E_NUM 8
#define I_DIM 1408

#define BM 128
#define BN 64
#define BK 32
// LDS tiles LINEAR (32 halves = 64B/row) for global_load_lds, double-buffered.
// Bank-conflict fix: XOR chunk swizzle chunk' = chunk ^ ((row>>1)&3) applied to
// BOTH the global source address and the ds_read address (rule #21).
// Pipeline (T14, safe): issue next tile's global_load_lds BEFORE compute of the
// current tile; __syncthreads() (fence+barrier+vmcnt drain) AFTER compute.
// One barrier per K-step; stage latency hides under the MFMAs.
// NOTE: raw s_barrier is IntrNoMem (not a compiler fence) — round-3's counted
// vmcnt + bare s_barrier raced (LDS reads hoisted across the barrier).

typedef __attribute__((ext_vector_type(8))) _Float16 half8;
typedef __attribute__((ext_vector_type(4))) _Float16 half4v;
typedef __attribute__((ext_vector_type(4))) float f32x4;

__device__ __forceinline__ void gload_lds16(const void* g, void* l) {
    __builtin_amdgcn_global_load_lds(
        (const __attribute__((address_space(1))) unsigned int*)g,
        (__attribute__((address_space(3))) unsigned int*)l, 16, 0, 0);
}

// ---------------- prep: x fp32 -> fp16 ----------------
__global__ __launch_bounds__(256) void xconv_kernel(
    const float* __restrict__ x, _Float16* __restrict__ xh)
{
    size_t i = ((size_t)blockIdx.x * 256 + threadIdx.x) * 4;
    float4 v = *(const float4*)(x + i);
    half4v hv = {(_Float16)v.x, (_Float16)v.y, (_Float16)v.z, (_Float16)v.w};
    *(half4v*)(xh + i) = hv;
}

// ---------------- prep: W fp32 [K][N] -> fp16 [N][K] (batched) ----------------
// 64x64 tile; 64B contiguous reads, 32B contiguous fp16 writes per lane.
__global__ __launch_bounds__(256) void tconv_kernel(
    const float* __restrict__ src, _Float16* __restrict__ dst, int K, int N)
{
    __shared__ float tile[64][65];
    const size_t msz = (size_t)K * N;
    const float* s = src + (size_t)blockIdx.z * msz;
    _Float16*    d = dst + (size_t)blockIdx.z * msz;
    const int k0 = blockIdx.y * 64;
    const int n0 = blockIdx.x * 64;
    const int tid = threadIdx.x;
    {
        int r = tid >> 2, c = (tid & 3) * 16;
        const float* sp = s + (size_t)(k0 + r) * N + n0 + c;
#pragma unroll
        for (int j = 0; j < 4; ++j) {
            float4 v = *(const float4*)(sp + j * 4);
            tile[r][c + j*4 + 0] = v.x; tile[r][c + j*4 + 1] = v.y;
            tile[r][c + j*4 + 2] = v.z; tile[r][c + j*4 + 3] = v.w;
        }
    }
    __syncthreads();
    {
        int n = tid >> 2, kq = (tid & 3) * 16;
        half8 h0, h1;
#pragma unroll
        for (int i = 0; i < 8; ++i) {
            h0[i] = (_Float16)tile[kq + i][n];
            h1[i] = (_Float16)tile[kq + 8 + i][n];
        }
        _Float16* dp = d + (size_t)(n0 + n) * K + k0 + kq;
        *(half8*)dp       = h0;
        *(half8*)(dp + 8) = h1;
    }
}

// ---------------- router: logits -> softmax -> top2 -> renorm ----------------
__global__ __launch_bounds__(64) void router_kernel(
    const float* __restrict__ x, const float* __restrict__ gw,
    int* __restrict__ cnt, int* __restrict__ tk_e, float* __restrict__ tk_w)
{
    const int t = blockIdx.x;
    const int lane = threadIdx.x;
    const float* xr = x + (size_t)t * H_DIM;
    float acc[8];
#pragma unroll
    for (int e = 0; e < 8; ++e) acc[e] = 0.f;
    for (int h = lane; h < H_DIM; h += 64) {
        float xv = xr[h];
        const float4* g4 = (const float4*)(gw + (size_t)h * 8);
        float4 ga = g4[0], gb = g4[1];
        acc[0] += xv * ga.x; acc[1] += xv * ga.y;
        acc[2] += xv * ga.z; acc[3] += xv * ga.w;
        acc[4] += xv * gb.x; acc[5] += xv * gb.y;
        acc[6] += xv * gb.z; acc[7] += xv * gb.w;
    }
#pragma unroll
    for (int e = 0; e < 8; ++e) {
#pragma unroll
        for (int off = 32; off > 0; off >>= 1)
            acc[e] += __shfl_xor(acc[e], off, 64);
    }
    if (lane == 0) {
        float mx = acc[0];
#pragma unroll
        for (int e = 1; e < 8; ++e) mx = fmaxf(mx, acc[e]);
        float p[8], sum = 0.f;
#pragma unroll
        for (int e = 0; e < 8; ++e) { p[e] = __expf(acc[e] - mx); sum += p[e]; }
        float inv = 1.f / sum;
#pragma unroll
        for (int e = 0; e < 8; ++e) p[e] *= inv;
        int e0 = 0;
#pragma unroll
        for (int e = 1; e < 8; ++e) if (p[e] > p[e0]) e0 = e;
        int e1 = (e0 == 0) ? 1 : 0;
#pragma unroll
        for (int e = 0; e < 8; ++e) if (e != e0 && p[e] > p[e1]) e1 = e;
        float w0 = p[e0], w1 = p[e1];
        float invw = 1.f / (w0 + w1 + 1e-6f);
        tk_e[2*t] = e0;      tk_e[2*t+1] = e1;
        tk_w[2*t] = w0*invw; tk_w[2*t+1] = w1*invw;
        atomicAdd(&cnt[e0], 1);
        atomicAdd(&cnt[e1], 1);
    }
}

// ---------------- tiny exclusive scan over 8 expert counts ----------------
__global__ void scan_kernel(const int* __restrict__ cnt, int* __restrict__ offs)
{
    if (threadIdx.x == 0) {
        int o = 0;
        for (int e = 0; e < 8; ++e) { offs[e] = o; o += cnt[e]; }
    }
}

// ---------------- scatter tokens into per-expert compact lists ----------------
__global__ __launch_bounds__(256) void scatter_kernel(
    const int* __restrict__ tk_e, const float* __restrict__ tk_w,
    const int* __restrict__ offs, int* __restrict__ fill,
    int* __restrict__ tokens, float* __restrict__ warr)
{
    int t = blockIdx.x * 256 + threadIdx.x;
    if (t >= T_TOK) return;
#pragma unroll
    for (int k = 0; k < 2; ++k) {
        int e = tk_e[2*t + k];
        int s = atomicAdd(&fill[e], 1);
        int idx = offs[e] + s;
        tokens[idx] = t;
        warr[idx]   = tk_w[2*t + k];
    }
}

// ---------------- GEMM1: h = silu(X Wg) * (X Wu), gathered rows ----------------
__global__ __launch_bounds__(256) void gemm1_kernel(
    const _Float16* __restrict__ xh,
    const _Float16* __restrict__ egt, const _Float16* __restrict__ eut,
    const _Float16* __restrict__ sgt, const _Float16* __restrict__ sut,
    const int* __restrict__ cnt, const int* __restrict__ offs,
    const int* __restrict__ tokens, _Float16* __restrict__ hbuf)
{
    const int p = blockIdx.z;
    int count, rowbase;
    const _Float16 *Wg, *Wu;
    const int* tokptr = nullptr;
    if (p == 0) {
        count = T_TOK; rowbase = 0;
        Wg = sgt; Wu = sut;
    } else {
        int e = p - 1;
        count = cnt[e];
        int ob = offs[e];
        rowbase = T_TOK + ob;
        tokptr = tokens + ob;
        Wg = egt + (size_t)e * I_DIM * H_DIM;
        Wu = eut + (size_t)e * I_DIM * H_DIM;
    }
    const int m0 = blockIdx.y * BM;
    if (m0 >= count) return;
    const int n0 = blockIdx.x * BN;
    const int tid = threadIdx.x;

    __shared__ _Float16 Asm[2][BM * BK];     // 2 x 128 x 32 halves, linear
    __shared__ _Float16 Bg_sm[2][BN * BK];
    __shared__ _Float16 Bu_sm[2][BN * BK];
    __shared__ int toksm[BM];

    if (tid < BM) {
        int s = m0 + tid;
        int t;
        if (p == 0) t = (s < count) ? s : 0;
        else        t = (s < count) ? tokptr[s] : 0;
        toksm[tid] = t;
    }
    __syncthreads();

    const int lane = tid & 63, wid = tid >> 6;
    const int wm = (wid >> 1) * 64, wn = (wid & 1) * 32;
    const int quad = lane >> 4, l16 = lane & 15;

    // ---- staging geometry: 16B chunks; row r = tid>>2, chunk c = tid&3 ----
    const int rq = tid >> 2;
    const int sc = (tid & 3) ^ ((rq >> 1) & 3);   // swizzled source chunk
    const _Float16* pA0 = xh + (size_t)toksm[rq]      * H_DIM + sc * 8;
    const _Float16* pA1 = xh + (size_t)toksm[rq + 64] * H_DIM + sc * 8;
    const _Float16* pBg = Wg + (size_t)(n0 + rq) * H_DIM + sc * 8;
    const _Float16* pBu = Wu + (size_t)(n0 + rq) * H_DIM + sc * 8;
    // per-buffer LDS destinations (all compile-time selected)
    _Float16* lA0_0 = &Asm[0][(wid * 64) * 8];
    _Float16* lA0_1 = &Asm[1][(wid * 64) * 8];
    _Float16* lA1_0 = &Asm[0][(256 + wid * 64) * 8];
    _Float16* lA1_1 = &Asm[1][(256 + wid * 64) * 8];
    _Float16* lBg_0 = &Bg_sm[0][(wid * 64) * 8];
    _Float16* lBg_1 = &Bg_sm[1][(wid * 64) * 8];
    _Float16* lBu_0 = &Bu_sm[0][(wid * 64) * 8];
    _Float16* lBu_1 = &Bu_sm[1][(wid * 64) * 8];

    const int rsw = (l16 >> 1) & 3;               // fragment-read swizzle

    f32x4 zero4 = {0.f, 0.f, 0.f, 0.f};
    f32x4 accg[4][2], accu[4][2];
#pragma unroll
    for (int mt = 0; mt < 4; ++mt)
#pragma unroll
        for (int nt = 0; nt < 2; ++nt) { accg[mt][nt] = zero4; accu[mt][nt] = zero4; }

    auto stage_to = [&](_Float16* dA0, _Float16* dA1, _Float16* dBg, _Float16* dBu) {
        gload_lds16(pA0, dA0);
        gload_lds16(pA1, dA1);
        gload_lds16(pBg, dBg);
        gload_lds16(pBu, dBu);
        pA0 += BK; pA1 += BK; pBg += BK; pBu += BK;
    };
    auto compute = [&](const _Float16* Ab, const _Float16* Bgb, const _Float16* Bub) {
        half8 a[4], bg[2], bu[2];
#pragma unroll
        for (int mt = 0; mt < 4; ++mt)
            a[mt] = *(const half8*)&Ab[(wm + mt*16 + l16) * BK + (quad ^ rsw) * 8];
#pragma unroll
        for (int nt = 0; nt < 2; ++nt) {
            bg[nt] = *(const half8*)&Bgb[(wn + nt*16 + l16) * BK + (quad ^ rsw) * 8];
            bu[nt] = *(const half8*)&Bub[(wn + nt*16 + l16) * BK + (quad ^ rsw) * 8];
        }
#pragma unroll
        for (int mt = 0; mt < 4; ++mt)
#pragma unroll
            for (int nt = 0; nt < 2; ++nt) {
                accg[mt][nt] = __builtin_amdgcn_mfma_f32_16x16x32_f16(a[mt], bg[nt], accg[mt][nt], 0, 0, 0);
                accu[mt][nt] = __builtin_amdgcn_mfma_f32_16x16x32_f16(a[mt], bu[nt], accu[mt][nt], 0, 0, 0);
            }
    };

    // prologue: stage tile 0 -> buf0, full drain
    stage_to(lA0_0, lA1_0, lBg_0, lBu_0);
    __syncthreads();

    const int NT = H_DIM / BK;   // 32 (even)
    for (int t = 0; t < NT; t += 2) {
        // phase 0: issue tile t+1 -> buf1 (always valid: NT even), compute buf0
        stage_to(lA0_1, lA1_1, lBg_1, lBu_1);
        compute(&Asm[0][0], &Bg_sm[0][0], &Bu_sm[0][0]);
        __syncthreads();                         // drains tile t+1 loads
        // phase 1: issue tile t+2 -> buf0 (if any), compute buf1
        if (t + 2 < NT)
            stage_to(lA0_0, lA1_0, lBg_0, lBu_0);
        compute(&Asm[1][0], &Bg_sm[1][0], &Bu_sm[1][0]);
        __syncthreads();                         // drains tile t+2 loads
    }

    // epilogue: h = silu(g)*u, store fp16 row-major [slot][I]
#pragma unroll
    for (int mt = 0; mt < 4; ++mt) {
#pragma unroll
        for (int nt = 0; nt < 2; ++nt) {
            int icol = n0 + wn + nt*16 + l16;
#pragma unroll
            for (int rg = 0; rg < 4; ++rg) {
                int s = m0 + wm + mt*16 + quad*4 + rg;
                if (s < count) {
                    float g = accg[mt][nt][rg];
                    float u = accu[mt][nt][rg];
                    float hval = (g / (1.f + __expf(-g))) * u;
                    hbuf[(size_t)(rowbase + s) * I_DIM + icol] = (_Float16)hval;
                }
            }
        }
    }
}

// ---------------- GEMM2: out[t] += w * (h Wd), atomic scatter-add ----------------
__global__ __launch_bounds__(256) void gemm2_kernel(
    const _Float16* __restrict__ edt, const _Float16* __restrict__ sdt,
    const int* __restrict__ cnt, const int* __restrict__ offs,
    const int* __restrict__ tokens, const float* __restrict__ warr,
    const _Float16* __restrict__ hbuf, float* __restrict__ out)
{
    const int p = blockIdx.z;
    int count, rowbase;
    const _Float16* W;
    const int* tokptr = nullptr;
    const float* wptr = nullptr;
    if (p == 0) { count = T_TOK; rowbase = 0; W = sdt; }
    else {
        int e = p - 1;
        count = cnt[e];
        int ob = offs[e];
        rowbase = T_TOK + ob;
        tokptr = tokens + ob;
        wptr = warr + ob;
        W = edt + (size_t)e * H_DIM * I_DIM;
    }
    const int m0 = blockIdx.y * BM;
    if (m0 >= count) return;
    const int n0 = blockIdx.x * BN;
    const int tid = threadIdx.x;

    __shared__ _Float16 Asm[2][BM * BK];
    __shared__ _Float16 Bsm[2][BN * BK];
    __shared__ int toksm[BM];
    __shared__ float wsm[BM];

    if (tid < BM) {
        int s = m0 + tid;
        if (s < count) {
            toksm[tid] = p ? tokptr[s] : s;
            wsm[tid]   = p ? wptr[s]   : 1.f;
        } else { toksm[tid] = 0; wsm[tid] = 0.f; }
    }
    __syncthreads();

    const int lane = tid & 63, wid = tid >> 6;
    const int wm = (wid >> 1) * 64, wn = (wid & 1) * 32;
    const int quad = lane >> 4, l16 = lane & 15;

    const int rq = tid >> 2;
    const int sc = (tid & 3) ^ ((rq >> 1) & 3);
    int s0 = m0 + rq;       s0 = (s0 < count) ? s0 : count - 1;
    int s1 = m0 + 64 + rq;  s1 = (s1 < count) ? s1 : count - 1;
    const _Float16* pA0 = hbuf + (size_t)(rowbase + s0) * I_DIM + sc * 8;
    const _Float16* pA1 = hbuf + (size_t)(rowbase + s1) * I_DIM + sc * 8;
    const _Float16* pB  = W    + (size_t)(n0 + rq) * I_DIM + sc * 8;
    _Float16* lA0_0 = &Asm[0][(wid * 64) * 8];
    _Float16* lA0_1 = &Asm[1][(wid * 64) * 8];
    _Float16* lA1_0 = &Asm[0][(256 + wid * 64) * 8];
    _Float16* lA1_1 = &Asm[1][(256 + wid * 64) * 8];
    _Float16* lB_0  = &Bsm[0][(wid * 64) * 8];
    _Float16* lB_1  = &Bsm[1][(wid * 64) * 8];

    const int rsw = (l16 >> 1) & 3;

    f32x4 zero4 = {0.f, 0.f, 0.f, 0.f};
    f32x4 acc[4][2];
#pragma unroll
    for (int mt = 0; mt < 4; ++mt)
#pragma unroll
        for (int nt = 0; nt < 2; ++nt) acc[mt][nt] = zero4;

    auto stage_to = [&](_Float16* dA0, _Float16* dA1, _Float16* dB) {
        gload_lds16(pA0, dA0);
        gload_lds16(pA1, dA1);
        gload_lds16(pB,  dB);
        pA0 += BK; pA1 += BK; pB += BK;
    };
    auto compute = [&](const _Float16* Ab, const _Float16* Bb) {
        half8 a[4], b[2];
#pragma unroll
        for (int mt = 0; mt < 4; ++mt)
            a[mt] = *(const half8*)&Ab[(wm + mt*16 + l16) * BK + (quad ^ rsw) * 8];
#pragma unroll
        for (int nt = 0; nt < 2; ++nt)
            b[nt] = *(const half8*)&Bb[(wn + nt*16 + l16) * BK + (quad ^ rsw) * 8];
#pragma unroll
        for (int mt = 0; mt < 4; ++mt)
#pragma unroll
            for (int nt = 0; nt < 2; ++nt)
                acc[mt][nt] = __builtin_amdgcn_mfma_f32_16x16x32_f16(a[mt], b[nt], acc[mt][nt], 0, 0, 0);
    };

    stage_to(lA0_0, lA1_0, lB_0);
    __syncthreads();

    const int NT = I_DIM / BK;   // 44 (even)
    for (int t = 0; t < NT; t += 2) {
        stage_to(lA0_1, lA1_1, lB_1);
        compute(&Asm[0][0], &Bsm[0][0]);
        __syncthreads();
        if (t + 2 < NT)
            stage_to(lA0_0, lA1_0, lB_0);
        compute(&Asm[1][0], &Bsm[1][0]);
        __syncthreads();
    }

#pragma unroll
    for (int mt = 0; mt < 4; ++mt) {
#pragma unroll
        for (int nt = 0; nt < 2; ++nt) {
            int n = n0 + wn + nt*16 + l16;
#pragma unroll
            for (int rg = 0; rg < 4; ++rg) {
                int mloc = wm + mt*16 + quad*4 + rg;
                int s = m0 + mloc;
                if (s < count) {
                    int t = toksm[mloc];
                    float wgt = wsm[mloc];
                    atomicAdd(out + (size_t)t * H_DIM + n, wgt * acc[mt][nt][rg]);
                }
            }
        }
    }
}

// ---------------- launch ----------------
extern "C" void kernel_launch(void* const* d_in, const int* in_sizes, int n_in,
                              void* d_out, int out_size, void* d_ws, size_t ws_size,
                              hipStream_t stream)
{
    const float* x  = (const float*)d_in[0];
    const float* gw = (const float*)d_in[1];
    const float* eg = (const float*)d_in[2];
    const float* eu = (const float*)d_in[3];
    const float* ed = (const float*)d_in[4];
    const float* sg = (const float*)d_in[5];
    const float* su = (const float*)d_in[6];
    const float* sd = (const float*)d_in[7];
    float* out = (float*)d_out;

    char* ws = (char*)d_ws;
    int*   cnt    = (int*)(ws + 0);          // 8 ints
    int*   fill   = (int*)(ws + 32);         // 8 ints
    int*   offs   = (int*)(ws + 64);         // 8 ints
    int*   tk_e   = (int*)(ws + 128);        // 2T ints
    float* tk_w   = (float*)(ws + 128 + 65536);
    int*   tokens = (int*)(ws + 128 + 2*65536);
    float* warr   = (float*)(ws + 128 + 3*65536);

    _Float16* hbuf = (_Float16*)(ws + 524288);           // 3T x I fp16 ~ 69.2 MB
    _Float16* xh   = hbuf + (size_t)3 * T_TOK * I_DIM;   // T x H fp16 ~ 16.8 MB
    _Float16* egt  = xh  + (size_t)T_TOK * H_DIM;        // E x I x H fp16 ~ 23.1 MB
    _Float16* eut  = egt + (size_t)E_NUM * I_DIM * H_DIM;
    _Float16* edt  = eut + (size_t)E_NUM * I_DIM * H_DIM; // E x H x I fp16
    _Float16* sgt  = edt + (size_t)E_NUM * H_DIM * I_DIM; // I x H fp16
    _Float16* sut  = sgt + (size_t)I_DIM * H_DIM;
    _Float16* sdt  = sut + (size_t)I_DIM * H_DIM;         // H x I fp16
    (void)ws_size;

    hipMemsetAsync(d_out, 0, (size_t)out_size * sizeof(float), stream);
    hipMemsetAsync(ws, 0, 96, stream);

    // prep: fp16 conversion + weight transposition
    xconv_kernel<<<(T_TOK * H_DIM) / 1024, 256, 0, stream>>>(x, xh);
    tconv_kernel<<<dim3(I_DIM/64, H_DIM/64, E_NUM), 256, 0, stream>>>(eg, egt, H_DIM, I_DIM);
    tconv_kernel<<<dim3(I_DIM/64, H_DIM/64, E_NUM), 256, 0, stream>>>(eu, eut, H_DIM, I_DIM);
    tconv_kernel<<<dim3(H_DIM/64, I_DIM/64, E_NUM), 256, 0, stream>>>(ed, edt, I_DIM, H_DIM);
    tconv_kernel<<<dim3(I_DIM/64, H_DIM/64, 1), 256, 0, stream>>>(sg, sgt, H_DIM, I_DIM);
    tconv_kernel<<<dim3(I_DIM/64, H_DIM/64, 1), 256, 0, stream>>>(su, sut, H_DIM, I_DIM);
    tconv_kernel<<<dim3(H_DIM/64, I_DIM/64, 1), 256, 0, stream>>>(sd, sdt, I_DIM, H_DIM);

    router_kernel<<<T_TOK, 64, 0, stream>>>(x, gw, cnt, tk_e, tk_w);
    scan_kernel<<<1, 64, 0, stream>>>(cnt, offs);
    scatter_kernel<<<T_TOK / 256, 256, 0, stream>>>(tk_e, tk_w, offs, fill, tokens, warr);
    gemm1_kernel<<<dim3(I_DIM / BN, T_TOK / BM, 9), 256, 0, stream>>>(
        xh, egt, eut, sgt, sut, cnt, offs, tokens, hbuf);
    gemm2_kernel<<<dim3(H_DIM / BN, T_TOK / BM, 9), 256, 0, stream>>>(
        edt, sdt, cnt, offs, tokens, warr, hbuf, out);
}

// Round 5
// 863.909 us; speedup vs baseline: 1.1106x; 1.1106x over previous
//
#include <hip/hip_runtime.h>
#include <hip/hip_fp16.h>

#define T_TOK 8192
#define H_DIM 1024
#define E_NUM 8
#define I_DIM 1408

#define BM 128
#define BN 64
#define BK 32
// LDS tiles LINEAR (32 halves = 64B/row) for global_load_lds, SINGLE buffer
// (round-2 verified structure: stage -> syncthreads -> compute -> syncthreads;
// explicit dbuf regressed in R4: occupancy loss, no drain avoided).
// Bank-conflict fix: XOR chunk swizzle chunk' = chunk ^ ((row>>1)&3) applied to
// BOTH the global source address and the ds_read address (rule #21).
// Block remap: by = ypanel*8 + xcd clusters same-A-panel blocks on one XCD
// (L2 panel residency) while spreading small routed-expert grids over all XCDs.

typedef __attribute__((ext_vector_type(8))) _Float16 half8;
typedef __attribute__((ext_vector_type(4))) _Float16 half4v;
typedef __attribute__((ext_vector_type(4))) float f32x4;

__device__ __forceinline__ void gload_lds16(const void* g, void* l) {
    __builtin_amdgcn_global_load_lds(
        (const __attribute__((address_space(1))) unsigned int*)g,
        (__attribute__((address_space(3))) unsigned int*)l, 16, 0, 0);
}

// ---------------- prep: x fp32 -> fp16 ----------------
__global__ __launch_bounds__(256) void xconv_kernel(
    const float* __restrict__ x, _Float16* __restrict__ xh)
{
    size_t i = ((size_t)blockIdx.x * 256 + threadIdx.x) * 4;
    float4 v = *(const float4*)(x + i);
    half4v hv = {(_Float16)v.x, (_Float16)v.y, (_Float16)v.z, (_Float16)v.w};
    *(half4v*)(xh + i) = hv;
}

// ---------------- prep: ALL weights fp32 [K][N] -> fp16 [N][K], one launch ----
// z: 0..7 eg, 8..15 eu, 16..23 ed, 24 sg, 25 su, 26 sd
__global__ __launch_bounds__(256) void tconv_all_kernel(
    const float* __restrict__ eg, const float* __restrict__ eu,
    const float* __restrict__ ed, const float* __restrict__ sg,
    const float* __restrict__ su, const float* __restrict__ sd,
    _Float16* __restrict__ egt, _Float16* __restrict__ eut,
    _Float16* __restrict__ edt, _Float16* __restrict__ sgt,
    _Float16* __restrict__ sut, _Float16* __restrict__ sdt)
{
    const size_t msz = (size_t)H_DIM * I_DIM;
    const int z = blockIdx.z;
    const float* src; _Float16* dst; int K, N;
    if (z < 8)       { src = eg + (size_t)z * msz;      dst = egt + (size_t)z * msz;      K = H_DIM; N = I_DIM; }
    else if (z < 16) { src = eu + (size_t)(z-8) * msz;  dst = eut + (size_t)(z-8) * msz;  K = H_DIM; N = I_DIM; }
    else if (z < 24) { src = ed + (size_t)(z-16) * msz; dst = edt + (size_t)(z-16) * msz; K = I_DIM; N = H_DIM; }
    else if (z == 24){ src = sg; dst = sgt; K = H_DIM; N = I_DIM; }
    else if (z == 25){ src = su; dst = sut; K = H_DIM; N = I_DIM; }
    else             { src = sd; dst = sdt; K = I_DIM; N = H_DIM; }

    const int k0 = blockIdx.y * 64;
    const int n0 = blockIdx.x * 64;
    if (k0 >= K || n0 >= N) return;

    __shared__ float tile[64][65];
    const int tid = threadIdx.x;
    {
        int r = tid >> 2, c = (tid & 3) * 16;
        const float* sp = src + (size_t)(k0 + r) * N + n0 + c;
#pragma unroll
        for (int j = 0; j < 4; ++j) {
            float4 v = *(const float4*)(sp + j * 4);
            tile[r][c + j*4 + 0] = v.x; tile[r][c + j*4 + 1] = v.y;
            tile[r][c + j*4 + 2] = v.z; tile[r][c + j*4 + 3] = v.w;
        }
    }
    __syncthreads();
    {
        int n = tid >> 2, kq = (tid & 3) * 16;
        half8 h0, h1;
#pragma unroll
        for (int i = 0; i < 8; ++i) {
            h0[i] = (_Float16)tile[kq + i][n];
            h1[i] = (_Float16)tile[kq + 8 + i][n];
        }
        _Float16* dp = dst + (size_t)(n0 + n) * K + k0 + kq;
        *(half8*)dp       = h0;
        *(half8*)(dp + 8) = h1;
    }
}

// ---------------- router: 4 tokens/block, one wave per token ----------------
__global__ __launch_bounds__(256) void router_kernel(
    const float* __restrict__ x, const float* __restrict__ gw,
    int* __restrict__ cnt, int* __restrict__ tk_e, float* __restrict__ tk_w)
{
    const int wid = threadIdx.x >> 6;
    const int lane = threadIdx.x & 63;
    const int t = blockIdx.x * 4 + wid;
    const float* xr = x + (size_t)t * H_DIM;
    float acc[8];
#pragma unroll
    for (int e = 0; e < 8; ++e) acc[e] = 0.f;
    for (int h = lane; h < H_DIM; h += 64) {
        float xv = xr[h];
        const float4* g4 = (const float4*)(gw + (size_t)h * 8);
        float4 ga = g4[0], gb = g4[1];
        acc[0] += xv * ga.x; acc[1] += xv * ga.y;
        acc[2] += xv * ga.z; acc[3] += xv * ga.w;
        acc[4] += xv * gb.x; acc[5] += xv * gb.y;
        acc[6] += xv * gb.z; acc[7] += xv * gb.w;
    }
#pragma unroll
    for (int e = 0; e < 8; ++e) {
#pragma unroll
        for (int off = 32; off > 0; off >>= 1)
            acc[e] += __shfl_xor(acc[e], off, 64);
    }
    if (lane == 0) {
        float mx = acc[0];
#pragma unroll
        for (int e = 1; e < 8; ++e) mx = fmaxf(mx, acc[e]);
        float p[8], sum = 0.f;
#pragma unroll
        for (int e = 0; e < 8; ++e) { p[e] = __expf(acc[e] - mx); sum += p[e]; }
        float inv = 1.f / sum;
#pragma unroll
        for (int e = 0; e < 8; ++e) p[e] *= inv;
        int e0 = 0;
#pragma unroll
        for (int e = 1; e < 8; ++e) if (p[e] > p[e0]) e0 = e;
        int e1 = (e0 == 0) ? 1 : 0;
#pragma unroll
        for (int e = 0; e < 8; ++e) if (e != e0 && p[e] > p[e1]) e1 = e;
        float w0 = p[e0], w1 = p[e1];
        float invw = 1.f / (w0 + w1 + 1e-6f);
        tk_e[2*t] = e0;      tk_e[2*t+1] = e1;
        tk_w[2*t] = w0*invw; tk_w[2*t+1] = w1*invw;
        atomicAdd(&cnt[e0], 1);
        atomicAdd(&cnt[e1], 1);
    }
}

// ---------------- tiny exclusive scan over 8 expert counts ----------------
__global__ void scan_kernel(const int* __restrict__ cnt, int* __restrict__ offs)
{
    if (threadIdx.x == 0) {
        int o = 0;
        for (int e = 0; e < 8; ++e) { offs[e] = o; o += cnt[e]; }
    }
}

// ---------------- scatter tokens into per-expert compact lists ----------------
__global__ __launch_bounds__(256) void scatter_kernel(
    const int* __restrict__ tk_e, const float* __restrict__ tk_w,
    const int* __restrict__ offs, int* __restrict__ fill,
    int* __restrict__ tokens, float* __restrict__ warr)
{
    int t = blockIdx.x * 256 + threadIdx.x;
    if (t >= T_TOK) return;
#pragma unroll
    for (int k = 0; k < 2; ++k) {
        int e = tk_e[2*t + k];
        int s = atomicAdd(&fill[e], 1);
        int idx = offs[e] + s;
        tokens[idx] = t;
        warr[idx]   = tk_w[2*t + k];
    }
}

// ---------------- GEMM1: h = silu(X Wg) * (X Wu), gathered rows ----------------
__global__ __launch_bounds__(256) void gemm1_kernel(
    const _Float16* __restrict__ xh,
    const _Float16* __restrict__ egt, const _Float16* __restrict__ eut,
    const _Float16* __restrict__ sgt, const _Float16* __restrict__ sut,
    const int* __restrict__ cnt, const int* __restrict__ offs,
    const int* __restrict__ tokens, _Float16* __restrict__ hbuf)
{
    const int p = blockIdx.z;
    int count, rowbase;
    const _Float16 *Wg, *Wu;
    const int* tokptr = nullptr;
    if (p == 0) {
        count = T_TOK; rowbase = 0;
        Wg = sgt; Wu = sut;
    } else {
        int e = p - 1;
        count = cnt[e];
        int ob = offs[e];
        rowbase = T_TOK + ob;
        tokptr = tokens + ob;
        Wg = egt + (size_t)e * I_DIM * H_DIM;
        Wu = eut + (size_t)e * I_DIM * H_DIM;
    }
    // panel-clustered remap: blocks sharing an A-panel (same by) get the same
    // XCD (raw%8) and consecutive dispatch slots; active by spans all xcd even
    // for small routed counts (by = ypanel*8 + xcd).
    const int GX = I_DIM / BN;                 // 22
    int raw = blockIdx.y * GX + blockIdx.x;
    int xcd = raw & 7, idx = raw >> 3;
    int bx = idx % GX, ypanel = idx / GX;      // ypanel in [0,8)
    int by = ypanel * 8 + xcd;                 // [0,64)
    const int m0 = by * BM;
    if (m0 >= count) return;
    const int n0 = bx * BN;
    const int tid = threadIdx.x;

    __shared__ _Float16 Asm[BM * BK];          // 128 x 32 halves, linear
    __shared__ _Float16 Bg_sm[BN * BK];
    __shared__ _Float16 Bu_sm[BN * BK];
    __shared__ int toksm[BM];

    if (tid < BM) {
        int s = m0 + tid;
        int t;
        if (p == 0) t = (s < count) ? s : 0;
        else        t = (s < count) ? tokptr[s] : 0;
        toksm[tid] = t;
    }
    __syncthreads();

    const int lane = tid & 63, wid = tid >> 6;
    const int wm = (wid >> 1) * 64, wn = (wid & 1) * 32;
    const int quad = lane >> 4, l16 = lane & 15;

    // staging: 16B chunks; row r = tid>>2, chunk c = tid&3; swizzled source
    const int rq = tid >> 2;
    const int sc = (tid & 3) ^ ((rq >> 1) & 3);
    const _Float16* pA0 = xh + (size_t)toksm[rq]      * H_DIM + sc * 8;
    const _Float16* pA1 = xh + (size_t)toksm[rq + 64] * H_DIM + sc * 8;
    const _Float16* pBg = Wg + (size_t)(n0 + rq) * H_DIM + sc * 8;
    const _Float16* pBu = Wu + (size_t)(n0 + rq) * H_DIM + sc * 8;
    _Float16* ldsA0 = &Asm  [(wid * 64)       * 8];
    _Float16* ldsA1 = &Asm  [(256 + wid * 64) * 8];
    _Float16* ldsBg = &Bg_sm[(wid * 64)       * 8];
    _Float16* ldsBu = &Bu_sm[(wid * 64)       * 8];

    const int rsw = (l16 >> 1) & 3;            // fragment-read swizzle

    f32x4 zero4 = {0.f, 0.f, 0.f, 0.f};
    f32x4 accg[4][2], accu[4][2];
#pragma unroll
    for (int mt = 0; mt < 4; ++mt)
#pragma unroll
        for (int nt = 0; nt < 2; ++nt) { accg[mt][nt] = zero4; accu[mt][nt] = zero4; }

    for (int k0 = 0; k0 < H_DIM; k0 += BK) {
        gload_lds16(pA0, ldsA0);
        gload_lds16(pA1, ldsA1);
        gload_lds16(pBg, ldsBg);
        gload_lds16(pBu, ldsBu);
        pA0 += BK; pA1 += BK; pBg += BK; pBu += BK;
        __syncthreads();

        half8 a[4], bg[2], bu[2];
#pragma unroll
        for (int mt = 0; mt < 4; ++mt)
            a[mt] = *(const half8*)&Asm[(wm + mt*16 + l16) * BK + (quad ^ rsw) * 8];
#pragma unroll
        for (int nt = 0; nt < 2; ++nt) {
            bg[nt] = *(const half8*)&Bg_sm[(wn + nt*16 + l16) * BK + (quad ^ rsw) * 8];
            bu[nt] = *(const half8*)&Bu_sm[(wn + nt*16 + l16) * BK + (quad ^ rsw) * 8];
        }
#pragma unroll
        for (int mt = 0; mt < 4; ++mt)
#pragma unroll
            for (int nt = 0; nt < 2; ++nt) {
                accg[mt][nt] = __builtin_amdgcn_mfma_f32_16x16x32_f16(a[mt], bg[nt], accg[mt][nt], 0, 0, 0);
                accu[mt][nt] = __builtin_amdgcn_mfma_f32_16x16x32_f16(a[mt], bu[nt], accu[mt][nt], 0, 0, 0);
            }
        __syncthreads();
    }

    // epilogue: h = silu(g)*u, store fp16 row-major [slot][I]
#pragma unroll
    for (int mt = 0; mt < 4; ++mt) {
#pragma unroll
        for (int nt = 0; nt < 2; ++nt) {
            int icol = n0 + wn + nt*16 + l16;
#pragma unroll
            for (int rg = 0; rg < 4; ++rg) {
                int s = m0 + wm + mt*16 + quad*4 + rg;
                if (s < count) {
                    float g = accg[mt][nt][rg];
                    float u = accu[mt][nt][rg];
                    float hval = (g / (1.f + __expf(-g))) * u;
                    hbuf[(size_t)(rowbase + s) * I_DIM + icol] = (_Float16)hval;
                }
            }
        }
    }
}

// ---------------- GEMM2: out[t] += w * (h Wd), atomic scatter-add ----------------
__global__ __launch_bounds__(256) void gemm2_kernel(
    const _Float16* __restrict__ edt, const _Float16* __restrict__ sdt,
    const int* __restrict__ cnt, const int* __restrict__ offs,
    const int* __restrict__ tokens, const float* __restrict__ warr,
    const _Float16* __restrict__ hbuf, float* __restrict__ out)
{
    const int p = blockIdx.z;
    int count, rowbase;
    const _Float16* W;
    const int* tokptr = nullptr;
    const float* wptr = nullptr;
    if (p == 0) { count = T_TOK; rowbase = 0; W = sdt; }
    else {
        int e = p - 1;
        count = cnt[e];
        int ob = offs[e];
        rowbase = T_TOK + ob;
        tokptr = tokens + ob;
        wptr = warr + ob;
        W = edt + (size_t)e * H_DIM * I_DIM;
    }
    const int GX = H_DIM / BN;                 // 16
    int raw = blockIdx.y * GX + blockIdx.x;
    int xcd = raw & 7, idx = raw >> 3;
    int bx = idx % GX, ypanel = idx / GX;
    int by = ypanel * 8 + xcd;
    const int m0 = by * BM;
    if (m0 >= count) return;
    const int n0 = bx * BN;
    const int tid = threadIdx.x;

    __shared__ _Float16 Asm[BM * BK];
    __shared__ _Float16 Bsm[BN * BK];
    __shared__ int toksm[BM];
    __shared__ float wsm[BM];

    if (tid < BM) {
        int s = m0 + tid;
        if (s < count) {
            toksm[tid] = p ? tokptr[s] : s;
            wsm[tid]   = p ? wptr[s]   : 1.f;
        } else { toksm[tid] = 0; wsm[tid] = 0.f; }
    }
    __syncthreads();

    const int lane = tid & 63, wid = tid >> 6;
    const int wm = (wid >> 1) * 64, wn = (wid & 1) * 32;
    const int quad = lane >> 4, l16 = lane & 15;

    const int rq = tid >> 2;
    const int sc = (tid & 3) ^ ((rq >> 1) & 3);
    int s0 = m0 + rq;       s0 = (s0 < count) ? s0 : count - 1;
    int s1 = m0 + 64 + rq;  s1 = (s1 < count) ? s1 : count - 1;
    const _Float16* pA0 = hbuf + (size_t)(rowbase + s0) * I_DIM + sc * 8;
    const _Float16* pA1 = hbuf + (size_t)(rowbase + s1) * I_DIM + sc * 8;
    const _Float16* pB  = W    + (size_t)(n0 + rq) * I_DIM + sc * 8;
    _Float16* ldsA0 = &Asm[(wid * 64)       * 8];
    _Float16* ldsA1 = &Asm[(256 + wid * 64) * 8];
    _Float16* ldsB  = &Bsm[(wid * 64)       * 8];

    const int rsw = (l16 >> 1) & 3;

    f32x4 zero4 = {0.f, 0.f, 0.f, 0.f};
    f32x4 acc[4][2];
#pragma unroll
    for (int mt = 0; mt < 4; ++mt)
#pragma unroll
        for (int nt = 0; nt < 2; ++nt) acc[mt][nt] = zero4;

    for (int k0 = 0; k0 < I_DIM; k0 += BK) {
        gload_lds16(pA0, ldsA0);
        gload_lds16(pA1, ldsA1);
        gload_lds16(pB,  ldsB);
        pA0 += BK; pA1 += BK; pB += BK;
        __syncthreads();

        half8 a[4], b[2];
#pragma unroll
        for (int mt = 0; mt < 4; ++mt)
            a[mt] = *(const half8*)&Asm[(wm + mt*16 + l16) * BK + (quad ^ rsw) * 8];
#pragma unroll
        for (int nt = 0; nt < 2; ++nt)
            b[nt] = *(const half8*)&Bsm[(wn + nt*16 + l16) * BK + (quad ^ rsw) * 8];
#pragma unroll
        for (int mt = 0; mt < 4; ++mt)
#pragma unroll
            for (int nt = 0; nt < 2; ++nt)
                acc[mt][nt] = __builtin_amdgcn_mfma_f32_16x16x32_f16(a[mt], b[nt], acc[mt][nt], 0, 0, 0);
        __syncthreads();
    }

#pragma unroll
    for (int mt = 0; mt < 4; ++mt) {
#pragma unroll
        for (int nt = 0; nt < 2; ++nt) {
            int n = n0 + wn + nt*16 + l16;
#pragma unroll
            for (int rg = 0; rg < 4; ++rg) {
                int mloc = wm + mt*16 + quad*4 + rg;
                int s = m0 + mloc;
                if (s < count) {
                    int t = toksm[mloc];
                    float wgt = wsm[mloc];
                    atomicAdd(out + (size_t)t * H_DIM + n, wgt * acc[mt][nt][rg]);
                }
            }
        }
    }
}

// ---------------- launch ----------------
extern "C" void kernel_launch(void* const* d_in, const int* in_sizes, int n_in,
                              void* d_out, int out_size, void* d_ws, size_t ws_size,
                              hipStream_t stream)
{
    const float* x  = (const float*)d_in[0];
    const float* gw = (const float*)d_in[1];
    const float* eg = (const float*)d_in[2];
    const float* eu = (const float*)d_in[3];
    const float* ed = (const float*)d_in[4];
    const float* sg = (const float*)d_in[5];
    const float* su = (const float*)d_in[6];
    const float* sd = (const float*)d_in[7];
    float* out = (float*)d_out;

    char* ws = (char*)d_ws;
    int*   cnt    = (int*)(ws + 0);          // 8 ints
    int*   fill   = (int*)(ws + 32);         // 8 ints
    int*   offs   = (int*)(ws + 64);         // 8 ints
    int*   tk_e   = (int*)(ws + 128);        // 2T ints
    float* tk_w   = (float*)(ws + 128 + 65536);
    int*   tokens = (int*)(ws + 128 + 2*65536);
    float* warr   = (float*)(ws + 128 + 3*65536);

    _Float16* hbuf = (_Float16*)(ws + 524288);           // 3T x I fp16 ~ 69.2 MB
    _Float16* xh   = hbuf + (size_t)3 * T_TOK * I_DIM;   // T x H fp16 ~ 16.8 MB
    _Float16* egt  = xh  + (size_t)T_TOK * H_DIM;        // E x I x H fp16 ~ 23.1 MB
    _Float16* eut  = egt + (size_t)E_NUM * I_DIM * H_DIM;
    _Float16* edt  = eut + (size_t)E_NUM * I_DIM * H_DIM; // E x H x I fp16
    _Float16* sgt  = edt + (size_t)E_NUM * H_DIM * I_DIM; // I x H fp16
    _Float16* sut  = sgt + (size_t)I_DIM * H_DIM;
    _Float16* sdt  = sut + (size_t)I_DIM * H_DIM;         // H x I fp16
    (void)ws_size;

    hipMemsetAsync(d_out, 0, (size_t)out_size * sizeof(float), stream);
    hipMemsetAsync(ws, 0, 96, stream);

    // prep: fp16 conversion + ALL weight transposes in one launch
    xconv_kernel<<<(T_TOK * H_DIM) / 1024, 256, 0, stream>>>(x, xh);
    tconv_all_kernel<<<dim3(I_DIM/64, I_DIM/64, 27), 256, 0, stream>>>(
        eg, eu, ed, sg, su, sd, egt, eut, edt, sgt, sut, sdt);

    router_kernel<<<T_TOK / 4, 256, 0, stream>>>(x, gw, cnt, tk_e, tk_w);
    scan_kernel<<<1, 64, 0, stream>>>(cnt, offs);
    scatter_kernel<<<T_TOK / 256, 256, 0, stream>>>(tk_e, tk_w, offs, fill, tokens, warr);
    gemm1_kernel<<<dim3(I_DIM / BN, T_TOK / BM, 9), 256, 0, stream>>>(
        xh, egt, eut, sgt, sut, cnt, offs, tokens, hbuf);
    gemm2_kernel<<<dim3(H_DIM / BN, T_TOK / BM, 9), 256, 0, stream>>>(
        edt, sdt, cnt, offs, tokens, warr, hbuf, out);
}